// Round 6
// baseline (334.570 us; speedup 1.0000x reference)
//
#include <hip/hip_runtime.h>
#include <hip/hip_bf16.h>

#define NN 32768
#define DEG 32
#define FF 128
#define OO 128
#define MB 32    // nodes per block
#define HP 136   // padded hbuf row pitch (shorts): 272 B -> conflict-free h reads

typedef __attribute__((ext_vector_type(8))) short bfrag;   // 8 bf16 (MFMA A/B operand)
typedef __attribute__((ext_vector_type(4))) float f32x4;   // MFMA C/D

#define K1 1.4426950408889634f

// cheap fp32->bf16: round-half-up == RNE except exact ties (prob 2^-16)
__device__ __forceinline__ unsigned short b16(float x) {
    unsigned u = __float_as_uint(x) + 0x8000u;
    return (unsigned short)(u >> 16);
}
__device__ __forceinline__ bfrag pack8(float4 a, float4 b) {
    bfrag r;
    r[0] = (short)b16(a.x); r[1] = (short)b16(a.y); r[2] = (short)b16(a.z); r[3] = (short)b16(a.w);
    r[4] = (short)b16(b.x); r[5] = (short)b16(b.y); r[6] = (short)b16(b.z); r[7] = (short)b16(b.w);
    return r;
}

__device__ __forceinline__ float fsig(float x, float nb) {      // sigmoid(x+b), nb=-K1*b
    return __builtin_amdgcn_rcpf(1.0f + __builtin_amdgcn_exp2f(fmaf(-K1, x, nb)));
}
__device__ __forceinline__ float ftanhb(float x, float pb) {    // tanh(x+b), pb=2*K1*b
    return fmaf(-2.0f, __builtin_amdgcn_rcpf(1.0f + __builtin_amdgcn_exp2f(fmaf(2.0f * K1, x, pb))), 1.0f);
}
__device__ __forceinline__ float ftanh(float x) {
    return fmaf(-2.0f, __builtin_amdgcn_rcpf(1.0f + __builtin_amdgcn_exp2f(2.0f * K1 * x)), 1.0f);
}

// async global->LDS, 16B per lane, dest = wave-uniform base + lane*16
__device__ __forceinline__ void gload16(const void* g, void* l) {
    __builtin_amdgcn_global_load_lds(
        (const __attribute__((address_space(1))) unsigned int*)g,
        (__attribute__((address_space(3))) unsigned int*)l, 16, 0, 0);
}

// -------- prep: weights/biases to bf16 (fold 1/deg into W2, combine biases) --------
__global__ void prep_weights(const float* __restrict__ wih, const float* __restrict__ whh,
                             const float* __restrict__ b_ih, const float* __restrict__ b_hh,
                             const float* __restrict__ w1, const float* __restrict__ b1,
                             const float* __restrict__ w2, const float* __restrict__ b2,
                             short* __restrict__ wihb, short* __restrict__ whhb,
                             short* __restrict__ w1b, short* __restrict__ w2b,
                             float* __restrict__ biasg, float* __restrict__ biaso)
{
    int i = blockIdx.x * blockDim.x + threadIdx.x;
    if (i < 512 * 128) { wihb[i] = (short)b16(wih[i]); whhb[i] = (short)b16(whh[i]); }
    if (i < 128 * 128) { w1b[i] = (short)b16(w1[i]); w2b[i] = (short)b16(w2[i] * 0.03125f); }
    if (i < 512) biasg[i] = b_ih[i] + b_hh[i];
    if (i < 128) biaso[i] = b1[i] + b2[i];
}

// -------- prep: feat fp32 -> bf16 (8 elements / thread) --------
__global__ void prep_feat(const float* __restrict__ f, short* __restrict__ fb) {
    int i = blockIdx.x * blockDim.x + threadIdx.x;       // 524288 threads
    const float4* p = reinterpret_cast<const float4*>(f) + (size_t)i * 2;
    float4 a = p[0], b = p[1];
    *reinterpret_cast<bfrag*>(fb + (size_t)i * 8) = pack8(a, b);
}

// 32 nodes/block, 8 waves. Wave w owns hidden/output cols [16w,16w+16).
// Weights in unified VGPR/AGPR regs.
// Checkerboard: even waves do [x-partial MFMAs][h-MFMA+act]x2; odd waves do
// [h-MFMA+act]x2[x-partial MFMAs]. Phases are pipe-complementary, so one
// wave's act (VALU/trans) overlaps the sibling wave's MFMAs on each SIMD.
template<bool BF16F>
__global__ __launch_bounds__(512, 2)
void sage_lstm_kernel(const float* __restrict__ featf, const short* __restrict__ featb,
                      const int* __restrict__ nidx,
                      const short* __restrict__ wihb, const short* __restrict__ whhb,
                      const short* __restrict__ w1b, const short* __restrict__ w2b,
                      const float* __restrict__ biasg, const float* __restrict__ biaso,
                      float* __restrict__ out)
{
    __shared__ short xbuf[2][MB * 128];   // x tiles, bf16, 4-row-XOR swizzle, ping-pong
    __shared__ short hbuf[2][MB * HP];    // h tiles, bf16, padded rows, ping-pong
    __shared__ int   idx_s[MB * DEG];

    const int tid  = (int)threadIdx.x;
    const int lane = tid & 63;
    const int wave = tid >> 6;
    const int n0   = (int)blockIdx.x * MB;

    const int srow = tid >> 4;                    // staging row 0..31
    const int cs   = tid & 15;                    // staging 8-elem column group
    const int chunk = (cs ^ (srow & 3)) * 8;      // inverse-swizzled source chunk (elements)

    idx_s[tid]       = nidx[n0 * DEG + tid];
    idx_s[512 + tid] = nidx[n0 * DEG + 512 + tid];

    char* const x0p = reinterpret_cast<char*>(xbuf[0]);
    char* const x1p = reinterpret_cast<char*>(xbuf[1]);
    char* const h0p = reinterpret_cast<char*>(hbuf[0]);
    char* const h1p = reinterpret_cast<char*>(hbuf[1]);

    {   bfrag z = {0, 0, 0, 0, 0, 0, 0, 0};
        reinterpret_cast<bfrag*>(h0p)[tid] = z;                 // 8192 B
        if (tid < 32) reinterpret_cast<bfrag*>(h0p + 8192)[tid] = z;   // -> 8704 B
    }

    // ---- weight B-fragments: lane holds 8 contiguous k for its column ----
    const int colw = wave * 16 + (lane & 15);
    bfrag wih[4][4], whh[4][4];
#pragma unroll
    for (int g = 0; g < 4; ++g) {
        const short* pih = wihb + (g * 128 + colw) * FF + (lane >> 4) * 8;
        const short* phh = whhb + (g * 128 + colw) * FF + (lane >> 4) * 8;
#pragma unroll
        for (int kt = 0; kt < 4; ++kt) {
            wih[g][kt] = *reinterpret_cast<const bfrag*>(pih + kt * 32);
            whh[g][kt] = *reinterpret_cast<const bfrag*>(phh + kt * 32);
        }
    }
    const float nbi = -K1 * biasg[colw];
    const float nbf = -K1 * biasg[128 + colw];
    const float pbg = 2.0f * K1 * biasg[256 + colw];
    const float nbo = -K1 * biasg[384 + colw];

    __syncthreads();   // B1: idx_s + hbuf[0] zeros visible

    // ---- stage x_0 -> xbuf[0], x_1 -> xbuf[1] ----
    if (BF16F) {
        gload16(featb + idx_s[srow * DEG + 0] * FF + chunk, x0p + wave * 1024);
        gload16(featb + idx_s[srow * DEG + 1] * FF + chunk, x1p + wave * 1024);
    } else {
        int sb = (srow * 256 + cs * 16) ^ ((srow & 3) << 4);
        {   const float4* p = reinterpret_cast<const float4*>(featf + idx_s[srow * DEG + 0] * FF + cs * 8);
            *reinterpret_cast<bfrag*>(x0p + sb) = pack8(p[0], p[1]); }
        {   const float4* p = reinterpret_cast<const float4*>(featf + idx_s[srow * DEG + 1] * FF + cs * 8);
            *reinterpret_cast<bfrag*>(x1p + sb) = pack8(p[0], p[1]); }
    }
    __syncthreads();   // B2: x_0, x_1 visible

    const int arow = lane & 15;
    const int asub = (lane >> 4) * 16;                         // bytes
    const int hr0  = (lane >> 4) * 4;
    // loop-invariant address pieces (bases; all per-kt/rt deltas are immediates)
    const int hoff = arow * HP + (lane >> 4) * 8;              // h-read base (elements)
    const int woff = hr0 * HP + colw;                          // h-write base (elements)
    const int xoff = (arow * 256 + asub) ^ ((arow & 3) << 4);  // x-read base (bytes)
    const bool evenw = (wave & 1) == 0;

    // h-MFMA: 4 kt reads at base+imm, padded layout
    auto mm4h = [&](const short* hb, int rtoff, const bfrag (&W)[4][4],
                    f32x4& vi, f32x4& vf, f32x4& vg, f32x4& vo) {
        bfrag a[4];
#pragma unroll
        for (int kt = 0; kt < 4; ++kt)
            a[kt] = *reinterpret_cast<const bfrag*>(hb + rtoff + kt * 32);
#pragma unroll
        for (int kt = 0; kt < 4; ++kt) {
            vi = __builtin_amdgcn_mfma_f32_16x16x32_bf16(a[kt], W[0][kt], vi, 0, 0, 0);
            vf = __builtin_amdgcn_mfma_f32_16x16x32_bf16(a[kt], W[1][kt], vf, 0, 0, 0);
            vg = __builtin_amdgcn_mfma_f32_16x16x32_bf16(a[kt], W[2][kt], vg, 0, 0, 0);
            vo = __builtin_amdgcn_mfma_f32_16x16x32_bf16(a[kt], W[3][kt], vo, 0, 0, 0);
        }
    };
    // x-MFMA: 4 kt reads at base+imm, 4-row-XOR layout
    auto mm4x = [&](const char* xb, int rtoff, const bfrag (&W)[4][4],
                    f32x4& vi, f32x4& vf, f32x4& vg, f32x4& vo) {
        bfrag a[4];
#pragma unroll
        for (int kt = 0; kt < 4; ++kt)
            a[kt] = *reinterpret_cast<const bfrag*>(xb + rtoff + kt * 64);
#pragma unroll
        for (int kt = 0; kt < 4; ++kt) {
            vi = __builtin_amdgcn_mfma_f32_16x16x32_bf16(a[kt], W[0][kt], vi, 0, 0, 0);
            vf = __builtin_amdgcn_mfma_f32_16x16x32_bf16(a[kt], W[1][kt], vf, 0, 0, 0);
            vg = __builtin_amdgcn_mfma_f32_16x16x32_bf16(a[kt], W[2][kt], vg, 0, 0, 0);
            vo = __builtin_amdgcn_mfma_f32_16x16x32_bf16(a[kt], W[3][kt], vo, 0, 0, 0);
        }
    };

    auto actw = [&](f32x4& gi, f32x4& gf, f32x4& gg, f32x4& go,
                    f32x4& cst, short* hw, int rt) {
#pragma unroll
        for (int r = 0; r < 4; ++r) {
            float iv = fsig(gi[r], nbi);
            float fv = fsig(gf[r], nbf);
            float gv = ftanhb(gg[r], pbg);
            float ov = fsig(go[r], nbo);
            float c  = fmaf(fv, cst[r], iv * gv);
            cst[r] = c;
            float h  = ov * ftanh(c);
            hw[(rt * 16 + r) * HP] = (short)b16(h);
        }
    };

    auto stage = [&](int t, char* xwr) {   // stage x_t into xwr
        int node = idx_s[srow * DEG + t];
        if (BF16F) {
            gload16(featb + node * FF + chunk, xwr + wave * 1024);
        } else {
            const float4* p = reinterpret_cast<const float4*>(featf + node * FF + cs * 8);
            int sb = (srow * 256 + cs * 16) ^ ((srow & 3) << 4);
            *reinterpret_cast<bfrag*>(xwr + sb) = pack8(p[0], p[1]);
        }
    };

    const f32x4 zz = {0.f, 0.f, 0.f, 0.f};
    f32x4 cs0 = zz, cs1 = zz;

    // gate/partial banks (A/B swap per step)
    f32x4 Ai0, Af0, Ag0, Ao0, Ai1, Af1, Ag1, Ao1;
    f32x4 Bi0, Bf0, Bg0, Bo0, Bi1, Bf1, Bg1, Bo1;

    // ---- prologue: bank A = x_0 partials ----
    Ai0 = zz; Af0 = zz; Ag0 = zz; Ao0 = zz;
    mm4x(x0p + xoff, 0, wih, Ai0, Af0, Ag0, Ao0);
    Ai1 = zz; Af1 = zz; Ag1 = zz; Ao1 = zz;
    mm4x(x0p + xoff, 4096, wih, Ai1, Af1, Ag1, Ao1);
    __syncthreads();   // B3: prologue reads of xbuf[0] done before t=0 restages it

#define STEP(T, Gi0,Gf0,Gg0,Go0, Gi1,Gf1,Gg1,Go1, Pi0,Pf0,Pg0,Po0, Pi1,Pf1,Pg1,Po1, HCUR,HNXT,XRD,XWR) \
    {                                                                                  \
        if ((T) < DEG - 2) stage((T) + 2, XWR);                                        \
        const short* hb = reinterpret_cast<const short*>(HCUR) + hoff;                 \
        short*       hw = reinterpret_cast<short*>(HNXT) + woff;                       \
        const char*  xb = (XRD) + xoff;                                                \
        if (evenw) {                                                                   \
            if ((T) < DEG - 1) {                                                       \
                Pi0 = zz; Pf0 = zz; Pg0 = zz; Po0 = zz;                                \
                mm4x(xb, 0, wih, Pi0, Pf0, Pg0, Po0);                                  \
                Pi1 = zz; Pf1 = zz; Pg1 = zz; Po1 = zz;                                \
                mm4x(xb, 4096, wih, Pi1, Pf1, Pg1, Po1);                               \
            }                                                                          \
            __builtin_amdgcn_sched_barrier(0);                                         \
            mm4h(hb, 0, whh, Gi0, Gf0, Gg0, Go0);                                      \
            actw(Gi0, Gf0, Gg0, Go0, cs0, hw, 0);                                      \
            mm4h(hb, 16 * HP, whh, Gi1, Gf1, Gg1, Go1);                                \
            actw(Gi1, Gf1, Gg1, Go1, cs1, hw, 1);                                      \
        } else {                                                                       \
            mm4h(hb, 0, whh, Gi0, Gf0, Gg0, Go0);                                      \
            actw(Gi0, Gf0, Gg0, Go0, cs0, hw, 0);                                      \
            mm4h(hb, 16 * HP, whh, Gi1, Gf1, Gg1, Go1);                                \
            actw(Gi1, Gf1, Gg1, Go1, cs1, hw, 1);                                      \
            __builtin_amdgcn_sched_barrier(0);                                         \
            if ((T) < DEG - 1) {                                                       \
                Pi0 = zz; Pf0 = zz; Pg0 = zz; Po0 = zz;                                \
                mm4x(xb, 0, wih, Pi0, Pf0, Pg0, Po0);                                  \
                Pi1 = zz; Pf1 = zz; Pg1 = zz; Po1 = zz;                                \
                mm4x(xb, 4096, wih, Pi1, Pf1, Pg1, Po1);                               \
            }                                                                          \
        }                                                                              \
        __syncthreads();                                                               \
    }

    for (int tt = 0; tt < DEG; tt += 2) {
        STEP(tt,     Ai0,Af0,Ag0,Ao0, Ai1,Af1,Ag1,Ao1,
                     Bi0,Bf0,Bg0,Bo0, Bi1,Bf1,Bg1,Bo1, h0p, h1p, x1p, x0p);
        STEP(tt + 1, Bi0,Bf0,Bg0,Bo0, Bi1,Bf1,Bg1,Bo1,
                     Ai0,Af0,Ag0,Ao0, Ai1,Af1,Ag1,Ao1, h1p, h0p, x0p, x1p);
    }
#undef STEP

    // ---- epilogue: out = feat@W1^T + (h/32)@W2^T + (b1+b2); h_final in hbuf[0] ----
    if (BF16F) {
        gload16(featb + (n0 + srow) * FF + chunk, x0p + wave * 1024);
    } else {
        const float4* p = reinterpret_cast<const float4*>(featf + (n0 + srow) * FF + cs * 8);
        int sb = (srow * 256 + cs * 16) ^ ((srow & 3) << 4);
        *reinterpret_cast<bfrag*>(x0p + sb) = pack8(p[0], p[1]);
    }
    __syncthreads();

    bfrag w1f[4], w2f[4];
#pragma unroll
    for (int kt = 0; kt < 4; ++kt) {
        w1f[kt] = *reinterpret_cast<const bfrag*>(w1b + colw * FF + kt * 32 + (lane >> 4) * 8);
        w2f[kt] = *reinterpret_cast<const bfrag*>(w2b + colw * FF + kt * 32 + (lane >> 4) * 8);
    }
    const float bb = biaso[colw];
#pragma unroll
    for (int rt = 0; rt < 2; ++rt) {
        bfrag fa[4], hfa[4];
#pragma unroll
        for (int kt = 0; kt < 4; ++kt) {
            fa[kt]  = *reinterpret_cast<const bfrag*>(x0p + xoff + rt * 4096 + kt * 64);
            hfa[kt] = *reinterpret_cast<const bfrag*>(reinterpret_cast<const short*>(h0p)
                                                      + hoff + rt * 16 * HP + kt * 32);
        }
        f32x4 acc = {0.f, 0.f, 0.f, 0.f};
#pragma unroll
        for (int kt = 0; kt < 4; ++kt) {
            acc = __builtin_amdgcn_mfma_f32_16x16x32_bf16(fa[kt],  w1f[kt], acc, 0, 0, 0);
            acc = __builtin_amdgcn_mfma_f32_16x16x32_bf16(hfa[kt], w2f[kt], acc, 0, 0, 0);
        }
#pragma unroll
        for (int r = 0; r < 4; ++r) {
            int orow = n0 + rt * 16 + hr0 + r;
            out[orow * OO + colw] = acc[r] + bb;
        }
    }
}

extern "C" void kernel_launch(void* const* d_in, const int* in_sizes, int n_in,
                              void* d_out, int out_size, void* d_ws, size_t ws_size,
                              hipStream_t stream)
{
    const float* feat = (const float*)d_in[0];
    const int*   nidx = (const int*)d_in[1];
    const float* W_ih = (const float*)d_in[2];
    const float* W_hh = (const float*)d_in[3];
    const float* b_ih = (const float*)d_in[4];
    const float* b_hh = (const float*)d_in[5];
    const float* W1   = (const float*)d_in[6];
    const float* b1   = (const float*)d_in[7];
    const float* W2   = (const float*)d_in[8];
    const float* b2   = (const float*)d_in[9];
    float* out = (float*)d_out;

    char* ws = (char*)d_ws;
    short* wihb  = (short*)(ws);             // 131072 B
    short* whhb  = (short*)(ws + 131072);    // 131072 B
    short* w1b   = (short*)(ws + 262144);    // 32768 B
    short* w2b   = (short*)(ws + 294912);    // 32768 B
    float* biasg = (float*)(ws + 327680);    // 2048 B
    float* biaso = (float*)(ws + 329728);    // 512 B
    short* featb = (short*)(ws + 330240);    // 8388608 B (16B-aligned)

    const size_t need = 330240 + (size_t)NN * FF * 2;
    const bool bf = ws_size >= need;

    prep_weights<<<256, 256, 0, stream>>>(W_ih, W_hh, b_ih, b_hh, W1, b1, W2, b2,
                                          wihb, whhb, w1b, w2b, biasg, biaso);
    if (bf) {
        prep_feat<<<2048, 256, 0, stream>>>(feat, featb);
        sage_lstm_kernel<true><<<NN / MB, 512, 0, stream>>>(feat, featb, nidx, wihb, whhb,
                                                            w1b, w2b, biasg, biaso, out);
    } else {
        sage_lstm_kernel<false><<<NN / MB, 512, 0, stream>>>(feat, featb, nidx, wihb, whhb,
                                                             w1b, w2b, biasg, biaso, out);
    }
}

// Round 7
// 306.623 us; speedup vs baseline: 1.0911x; 1.0911x over previous
//
#include <hip/hip_runtime.h>
#include <hip/hip_bf16.h>

#define NN 32768
#define DEG 32
#define FF 128
#define OO 128
#define MB 32   // nodes per block

typedef __attribute__((ext_vector_type(8))) short bfrag;   // 8 bf16 (MFMA A/B operand)
typedef __attribute__((ext_vector_type(4))) float f32x4;   // MFMA C/D

#define K1 1.4426950408889634f

// cheap fp32->bf16: round-half-up == RNE except exact ties (prob 2^-16)
__device__ __forceinline__ unsigned short b16(float x) {
    unsigned u = __float_as_uint(x) + 0x8000u;
    return (unsigned short)(u >> 16);
}
__device__ __forceinline__ bfrag pack8(float4 a, float4 b) {
    bfrag r;
    r[0] = (short)b16(a.x); r[1] = (short)b16(a.y); r[2] = (short)b16(a.z); r[3] = (short)b16(a.w);
    r[4] = (short)b16(b.x); r[5] = (short)b16(b.y); r[6] = (short)b16(b.z); r[7] = (short)b16(b.w);
    return r;
}

__device__ __forceinline__ float fsig(float x, float nb) {      // sigmoid(x+b), nb=-K1*b
    return __builtin_amdgcn_rcpf(1.0f + __builtin_amdgcn_exp2f(fmaf(-K1, x, nb)));
}
__device__ __forceinline__ float ftanhb(float x, float pb) {    // tanh(x+b), pb=2*K1*b
    return fmaf(-2.0f, __builtin_amdgcn_rcpf(1.0f + __builtin_amdgcn_exp2f(fmaf(2.0f * K1, x, pb))), 1.0f);
}
__device__ __forceinline__ float ftanh(float x) {
    return fmaf(-2.0f, __builtin_amdgcn_rcpf(1.0f + __builtin_amdgcn_exp2f(2.0f * K1 * x)), 1.0f);
}

// async global->LDS, 16B per lane, dest = wave-uniform base + lane*16
__device__ __forceinline__ void gload16(const void* g, void* l) {
    __builtin_amdgcn_global_load_lds(
        (const __attribute__((address_space(1))) unsigned int*)g,
        (__attribute__((address_space(3))) unsigned int*)l, 16, 0, 0);
}

// -------- prep: weights/biases to bf16 (fold 1/deg into W2, combine biases) --------
__global__ void prep_weights(const float* __restrict__ wih, const float* __restrict__ whh,
                             const float* __restrict__ b_ih, const float* __restrict__ b_hh,
                             const float* __restrict__ w1, const float* __restrict__ b1,
                             const float* __restrict__ w2, const float* __restrict__ b2,
                             short* __restrict__ wihb, short* __restrict__ whhb,
                             short* __restrict__ w1b, short* __restrict__ w2b,
                             float* __restrict__ biasg, float* __restrict__ biaso)
{
    int i = blockIdx.x * blockDim.x + threadIdx.x;
    if (i < 512 * 128) { wihb[i] = (short)b16(wih[i]); whhb[i] = (short)b16(whh[i]); }
    if (i < 128 * 128) { w1b[i] = (short)b16(w1[i]); w2b[i] = (short)b16(w2[i] * 0.03125f); }
    if (i < 512) biasg[i] = b_ih[i] + b_hh[i];
    if (i < 128) biaso[i] = b1[i] + b2[i];
}

// -------- prep: feat fp32 -> bf16 (8 elements / thread) --------
__global__ void prep_feat(const float* __restrict__ f, short* __restrict__ fb) {
    int i = blockIdx.x * blockDim.x + threadIdx.x;       // 524288 threads
    const float4* p = reinterpret_cast<const float4*>(f) + (size_t)i * 2;
    float4 a = p[0], b = p[1];
    *reinterpret_cast<bfrag*>(fb + (size_t)i * 8) = pack8(a, b);
}

// 32 nodes/block, 8 waves. Wave w owns hidden/output cols [16w,16w+16).
// Weights in unified VGPR/AGPR regs.
// Checkerboard across SIMD-siblings: waves w and w+4 share a SIMD (round-robin
// w%4 -> SIMD), so the role split keys on (wave>>2)&1. hi waves run
// [P-MFMAs][G+act][G+act]; lo waves run [G+act][G+act][P-MFMAs]. One wave's
// act (VALU/trans) overlaps the sibling's MFMA cluster each step.
template<bool BF16F>
__global__ __launch_bounds__(512, 2)
void sage_lstm_kernel(const float* __restrict__ featf, const short* __restrict__ featb,
                      const int* __restrict__ nidx,
                      const short* __restrict__ wihb, const short* __restrict__ whhb,
                      const short* __restrict__ w1b, const short* __restrict__ w2b,
                      const float* __restrict__ biasg, const float* __restrict__ biaso,
                      float* __restrict__ out)
{
    __shared__ short xbuf[2][MB * 128];   // x tiles, bf16, XOR-8 swizzled, ping-pong
    __shared__ short hbuf[2][MB * 128];   // h tiles, bf16, XOR-8 swizzled, ping-pong
    __shared__ int   idx_s[MB * DEG];

    const int tid  = (int)threadIdx.x;
    const int lane = tid & 63;
    const int wave = tid >> 6;
    const int n0   = (int)blockIdx.x * MB;

    const int srow = tid >> 4;                    // staging row 0..31
    const int cs   = tid & 15;                    // staging 8-elem column group
    const int chunk = (cs ^ (srow & 7)) * 8;      // inverse-swizzled source chunk (elements)

    idx_s[tid]       = nidx[n0 * DEG + tid];
    idx_s[512 + tid] = nidx[n0 * DEG + 512 + tid];
    {   bfrag z = {0, 0, 0, 0, 0, 0, 0, 0};
        reinterpret_cast<bfrag*>(hbuf[0])[tid] = z; }

    // ---- weight B-fragments: lane holds 8 contiguous k for its column ----
    const int colw = wave * 16 + (lane & 15);
    bfrag wih[4][4], whh[4][4];
#pragma unroll
    for (int g = 0; g < 4; ++g) {
        const short* pih = wihb + (g * 128 + colw) * FF + (lane >> 4) * 8;
        const short* phh = whhb + (g * 128 + colw) * FF + (lane >> 4) * 8;
#pragma unroll
        for (int kt = 0; kt < 4; ++kt) {
            wih[g][kt] = *reinterpret_cast<const bfrag*>(pih + kt * 32);
            whh[g][kt] = *reinterpret_cast<const bfrag*>(phh + kt * 32);
        }
    }
    const float nbi = -K1 * biasg[colw];
    const float nbf = -K1 * biasg[128 + colw];
    const float pbg = 2.0f * K1 * biasg[256 + colw];
    const float nbo = -K1 * biasg[384 + colw];

    __syncthreads();   // B1: idx_s + hbuf[0] zeros visible

    char* const x0p = reinterpret_cast<char*>(xbuf[0]);
    char* const x1p = reinterpret_cast<char*>(xbuf[1]);
    char* const h0p = reinterpret_cast<char*>(hbuf[0]);
    char* const h1p = reinterpret_cast<char*>(hbuf[1]);

    // ---- stage x_0 -> xbuf[0], x_1 -> xbuf[1] ----
    if (BF16F) {
        gload16(featb + idx_s[srow * DEG + 0] * FF + chunk, x0p + wave * 1024);
        gload16(featb + idx_s[srow * DEG + 1] * FF + chunk, x1p + wave * 1024);
    } else {
        int sb = (srow * 256 + cs * 16) ^ ((srow & 7) << 4);
        {   const float4* p = reinterpret_cast<const float4*>(featf + idx_s[srow * DEG + 0] * FF + cs * 8);
            *reinterpret_cast<bfrag*>(x0p + sb) = pack8(p[0], p[1]); }
        {   const float4* p = reinterpret_cast<const float4*>(featf + idx_s[srow * DEG + 1] * FF + cs * 8);
            *reinterpret_cast<bfrag*>(x1p + sb) = pack8(p[0], p[1]); }
    }
    __syncthreads();   // B2: x_0, x_1 visible

    const int arow = lane & 15;
    const int asub = (lane >> 4) * 16;
    const int hr0  = (lane >> 4) * 4;
    const int swz  = (arow & 7) << 4;
    const bool hi4 = ((wave >> 2) & 1) != 0;      // SIMD-sibling parity

    // 4-kt MFMA accumulate from LDS tile p (XOR-8 layout), row base rbase
    auto mm4 = [&](const char* p, int rbase, const bfrag (&W)[4][4],
                   f32x4& vi, f32x4& vf, f32x4& vg, f32x4& vo) {
        bfrag a[4];
#pragma unroll
        for (int kt = 0; kt < 4; ++kt)
            a[kt] = *reinterpret_cast<const bfrag*>(p + ((rbase * 256 + kt * 64 + asub) ^ swz));
#pragma unroll
        for (int kt = 0; kt < 4; ++kt) {
            vi = __builtin_amdgcn_mfma_f32_16x16x32_bf16(a[kt], W[0][kt], vi, 0, 0, 0);
            vf = __builtin_amdgcn_mfma_f32_16x16x32_bf16(a[kt], W[1][kt], vf, 0, 0, 0);
            vg = __builtin_amdgcn_mfma_f32_16x16x32_bf16(a[kt], W[2][kt], vg, 0, 0, 0);
            vo = __builtin_amdgcn_mfma_f32_16x16x32_bf16(a[kt], W[3][kt], vo, 0, 0, 0);
        }
    };

    auto actw = [&](f32x4& gi, f32x4& gf, f32x4& gg, f32x4& go,
                    f32x4& cst, char* hnxt, int rt) {
#pragma unroll
        for (int r = 0; r < 4; ++r) {
            float iv = fsig(gi[r], nbi);
            float fv = fsig(gf[r], nbf);
            float gv = ftanhb(gg[r], pbg);
            float ov = fsig(go[r], nbo);
            float c  = fmaf(fv, cst[r], iv * gv);
            cst[r] = c;
            float h  = ov * ftanh(c);
            int hrow = rt * 16 + hr0 + r;
            int hb   = (hrow * 256 + colw * 2) ^ ((hrow & 7) << 4);
            *reinterpret_cast<unsigned short*>(hnxt + hb) = b16(h);
        }
    };

    auto stage = [&](int t, char* xwr) {   // stage x_t into xwr
        int node = idx_s[srow * DEG + t];
        if (BF16F) {
            gload16(featb + node * FF + chunk, xwr + wave * 1024);
        } else {
            const float4* p = reinterpret_cast<const float4*>(featf + node * FF + cs * 8);
            int sb = (srow * 256 + cs * 16) ^ ((srow & 7) << 4);
            *reinterpret_cast<bfrag*>(xwr + sb) = pack8(p[0], p[1]);
        }
    };

    const f32x4 zz = {0.f, 0.f, 0.f, 0.f};
    f32x4 cs0 = zz, cs1 = zz;

    // gate/partial banks (A/B swap per step)
    f32x4 Ai0, Af0, Ag0, Ao0, Ai1, Af1, Ag1, Ao1;
    f32x4 Bi0, Bf0, Bg0, Bo0, Bi1, Bf1, Bg1, Bo1;

    // ---- prologue: bank A = x_0 partials ----
    Ai0 = zz; Af0 = zz; Ag0 = zz; Ao0 = zz;
    mm4(x0p, arow, wih, Ai0, Af0, Ag0, Ao0);
    Ai1 = zz; Af1 = zz; Ag1 = zz; Ao1 = zz;
    mm4(x0p, 16 + arow, wih, Ai1, Af1, Ag1, Ao1);
    __syncthreads();   // B3: prologue reads of xbuf[0] done before t=0 restages it

// P cluster: next-step x partials (independent of this step's act)
#define PCL(T, Pi0,Pf0,Pg0,Po0, Pi1,Pf1,Pg1,Po1, XRD)                                  \
        if ((T) < DEG - 1) {                                                           \
            Pi0 = zz; Pf0 = zz; Pg0 = zz; Po0 = zz;                                    \
            mm4(XRD, arow, wih, Pi0, Pf0, Pg0, Po0);                                   \
            Pi1 = zz; Pf1 = zz; Pg1 = zz; Po1 = zz;                                    \
            mm4(XRD, 16 + arow, wih, Pi1, Pf1, Pg1, Po1);                              \
        }

// G+act pair (prio-boosted MFMA clusters)
#define GACT(Gi0,Gf0,Gg0,Go0, Gi1,Gf1,Gg1,Go1, HCUR,HNXT)                              \
        __builtin_amdgcn_s_setprio(1);                                                 \
        mm4(HCUR, arow, whh, Gi0, Gf0, Gg0, Go0);                                      \
        __builtin_amdgcn_s_setprio(0);                                                 \
        actw(Gi0, Gf0, Gg0, Go0, cs0, HNXT, 0);                                        \
        __builtin_amdgcn_s_setprio(1);                                                 \
        mm4(HCUR, 16 + arow, whh, Gi1, Gf1, Gg1, Go1);                                 \
        __builtin_amdgcn_s_setprio(0);                                                 \
        actw(Gi1, Gf1, Gg1, Go1, cs1, HNXT, 1);

#define STEP_HI(T, Gi0,Gf0,Gg0,Go0, Gi1,Gf1,Gg1,Go1, Pi0,Pf0,Pg0,Po0, Pi1,Pf1,Pg1,Po1, HCUR,HNXT,XRD,XWR) \
    {                                                                                  \
        if ((T) < DEG - 2) stage((T) + 2, XWR);                                        \
        PCL(T, Pi0,Pf0,Pg0,Po0, Pi1,Pf1,Pg1,Po1, XRD)                                  \
        __builtin_amdgcn_sched_barrier(0);                                             \
        GACT(Gi0,Gf0,Gg0,Go0, Gi1,Gf1,Gg1,Go1, HCUR,HNXT)                              \
        __syncthreads();                                                               \
    }

#define STEP_LO(T, Gi0,Gf0,Gg0,Go0, Gi1,Gf1,Gg1,Go1, Pi0,Pf0,Pg0,Po0, Pi1,Pf1,Pg1,Po1, HCUR,HNXT,XRD,XWR) \
    {                                                                                  \
        if ((T) < DEG - 2) stage((T) + 2, XWR);                                        \
        GACT(Gi0,Gf0,Gg0,Go0, Gi1,Gf1,Gg1,Go1, HCUR,HNXT)                              \
        __builtin_amdgcn_sched_barrier(0);                                             \
        PCL(T, Pi0,Pf0,Pg0,Po0, Pi1,Pf1,Pg1,Po1, XRD)                                  \
        __syncthreads();                                                               \
    }

    if (hi4) {
#pragma unroll 1
        for (int tt = 0; tt < DEG; tt += 2) {
            STEP_HI(tt,     Ai0,Af0,Ag0,Ao0, Ai1,Af1,Ag1,Ao1,
                            Bi0,Bf0,Bg0,Bo0, Bi1,Bf1,Bg1,Bo1, h0p, h1p, x1p, x0p);
            STEP_HI(tt + 1, Bi0,Bf0,Bg0,Bo0, Bi1,Bf1,Bg1,Bo1,
                            Ai0,Af0,Ag0,Ao0, Ai1,Af1,Ag1,Ao1, h1p, h0p, x0p, x1p);
        }
    } else {
#pragma unroll 1
        for (int tt = 0; tt < DEG; tt += 2) {
            STEP_LO(tt,     Ai0,Af0,Ag0,Ao0, Ai1,Af1,Ag1,Ao1,
                            Bi0,Bf0,Bg0,Bo0, Bi1,Bf1,Bg1,Bo1, h0p, h1p, x1p, x0p);
            STEP_LO(tt + 1, Bi0,Bf0,Bg0,Bo0, Bi1,Bf1,Bg1,Bo1,
                            Ai0,Af0,Ag0,Ao0, Ai1,Af1,Ag1,Ao1, h1p, h0p, x0p, x1p);
        }
    }
#undef STEP_HI
#undef STEP_LO
#undef GACT
#undef PCL

    // ---- epilogue: out = feat@W1^T + (h/32)@W2^T + (b1+b2); h_final in hbuf[0] ----
    if (BF16F) {
        gload16(featb + (n0 + srow) * FF + chunk, x0p + wave * 1024);
    } else {
        const float4* p = reinterpret_cast<const float4*>(featf + (n0 + srow) * FF + cs * 8);
        int sb = (srow * 256 + cs * 16) ^ ((srow & 7) << 4);
        *reinterpret_cast<bfrag*>(x0p + sb) = pack8(p[0], p[1]);
    }
    __syncthreads();

    bfrag w1f[4], w2f[4];
#pragma unroll
    for (int kt = 0; kt < 4; ++kt) {
        w1f[kt] = *reinterpret_cast<const bfrag*>(w1b + colw * FF + kt * 32 + (lane >> 4) * 8);
        w2f[kt] = *reinterpret_cast<const bfrag*>(w2b + colw * FF + kt * 32 + (lane >> 4) * 8);
    }
    const float bb = biaso[colw];
#pragma unroll
    for (int rt = 0; rt < 2; ++rt) {
        const int rowr = rt * 16 + arow;
        bfrag fa[4], hfa[4];
#pragma unroll
        for (int kt = 0; kt < 4; ++kt) {
            int byte = (rowr * 256 + kt * 64 + asub) ^ swz;
            fa[kt]  = *reinterpret_cast<const bfrag*>(x0p + byte);
            hfa[kt] = *reinterpret_cast<const bfrag*>(h0p + byte);
        }
        f32x4 acc = {0.f, 0.f, 0.f, 0.f};
#pragma unroll
        for (int kt = 0; kt < 4; ++kt) {
            acc = __builtin_amdgcn_mfma_f32_16x16x32_bf16(fa[kt],  w1f[kt], acc, 0, 0, 0);
            acc = __builtin_amdgcn_mfma_f32_16x16x32_bf16(hfa[kt], w2f[kt], acc, 0, 0, 0);
        }
#pragma unroll
        for (int r = 0; r < 4; ++r) {
            int orow = n0 + rt * 16 + hr0 + r;
            out[orow * OO + colw] = acc[r] + bb;
        }
    }
}

extern "C" void kernel_launch(void* const* d_in, const int* in_sizes, int n_in,
                              void* d_out, int out_size, void* d_ws, size_t ws_size,
                              hipStream_t stream)
{
    const float* feat = (const float*)d_in[0];
    const int*   nidx = (const int*)d_in[1];
    const float* W_ih = (const float*)d_in[2];
    const float* W_hh = (const float*)d_in[3];
    const float* b_ih = (const float*)d_in[4];
    const float* b_hh = (const float*)d_in[5];
    const float* W1   = (const float*)d_in[6];
    const float* b1   = (const float*)d_in[7];
    const float* W2   = (const float*)d_in[8];
    const float* b2   = (const float*)d_in[9];
    float* out = (float*)d_out;

    char* ws = (char*)d_ws;
    short* wihb  = (short*)(ws);             // 131072 B
    short* whhb  = (short*)(ws + 131072);    // 131072 B
    short* w1b   = (short*)(ws + 262144);    // 32768 B
    short* w2b   = (short*)(ws + 294912);    // 32768 B
    float* biasg = (float*)(ws + 327680);    // 2048 B
    float* biaso = (float*)(ws + 329728);    // 512 B
    short* featb = (short*)(ws + 330240);    // 8388608 B (16B-aligned)

    const size_t need = 330240 + (size_t)NN * FF * 2;
    const bool bf = ws_size >= need;

    prep_weights<<<256, 256, 0, stream>>>(W_ih, W_hh, b_ih, b_hh, W1, b1, W2, b2,
                                          wihb, whhb, w1b, w2b, biasg, biaso);
    if (bf) {
        prep_feat<<<2048, 256, 0, stream>>>(feat, featb);
        sage_lstm_kernel<true><<<NN / MB, 512, 0, stream>>>(feat, featb, nidx, wihb, whhb,
                                                            w1b, w2b, biasg, biaso, out);
    } else {
        sage_lstm_kernel<false><<<NN / MB, 512, 0, stream>>>(feat, featb, nidx, wihb, whhb,
                                                             w1b, w2b, biasg, biaso, out);
    }
}